// Round 9
// baseline (1032.477 us; speedup 1.0000x reference)
//
#include <hip/hip_runtime.h>
#include <cstdint>

#define NTOK 8192
#define DMODEL 1024
#define HDDIM 4096
#define NVEC 32
#define WELEM (DMODEL * HDDIM)   // 4M elements per W

typedef float f32x4_v __attribute__((ext_vector_type(4)));
typedef __bf16 bf16x8 __attribute__((ext_vector_type(8)));
typedef unsigned short u16x4 __attribute__((ext_vector_type(4)));
typedef unsigned short u16x8 __attribute__((ext_vector_type(8)));

__device__ __forceinline__ unsigned short f2bf(float f) {
  union { float f; uint32_t u; } x; x.f = f;
  uint32_t r = (x.u + 0x7FFFu + ((x.u >> 16) & 1u)) >> 16;
  return (unsigned short)r;
}

__device__ __forceinline__ float gelu_fast(float x) {
  float t = x * x;
  float z = x * (2.3022082f + 0.1029440f * t);
  float e = exp2f(-z);
  return x / (1.0f + e);
}

#define VMCNT(n) asm volatile("s_waitcnt vmcnt(" #n ")" ::: "memory")

__device__ __forceinline__ void gload16(const unsigned short* g, unsigned short* lds)
{
  __builtin_amdgcn_global_load_lds((__attribute__((address_space(1))) void*)g,
                                   (__attribute__((address_space(3))) void*)lds,
                                   16, 0, 0);
}

// ---------------------------------------------------------------------------
// wrec: W_nat = sum_v c[v]*basis[v] as a FLAT 4M-elem streaming op.
// Block = 32KB contiguous chunk per v; thread = 8 x f32x4. No LDS.
// blocks 0..511 -> Wup, 512..1023 -> Wdn, 1024..1535 -> cvt inputs->bf16.
// REP: internal repetition for counter visibility (v-order staggered per rep).
// ---------------------------------------------------------------------------
template<int REP>
__global__ __launch_bounds__(256)
void wrec_kernel(const float* __restrict__ inputs,
                 const float* __restrict__ basis_up,
                 const float* __restrict__ basis_down,
                 const float* __restrict__ cup,
                 const float* __restrict__ cdn,
                 const int* __restrict__ eidx_p,
                 unsigned short* __restrict__ A_bf,
                 unsigned short* __restrict__ Wup_nat,
                 unsigned short* __restrict__ Wdn_nat)
{
  const int bid = blockIdx.x;
  const int t = threadIdx.x;
  for (int rep = 0; rep < REP; ++rep) {
    if (bid < 1024) {
      const bool up = bid < 512;
      const float* basis = up ? basis_up : basis_down;
      const float* coeffs = up ? cup : cdn;
      unsigned short* outp = up ? Wup_nat : Wdn_nat;
      const int cb = up ? bid : bid - 512;
      const int e = *eidx_p;
      f32x4_v acc[8];
      #pragma unroll
      for (int i = 0; i < 8; ++i) acc[i] = (f32x4_v){0.f, 0.f, 0.f, 0.f};
      const uint32_t base4 = (uint32_t)cb * 2048u + (uint32_t)t; // vec4 idx
      for (int vv = 0; vv < NVEC; ++vv) {
        const int v = (vv + bid + rep) & (NVEC - 1);
        const float cv = coeffs[e * NVEC + v];
        const f32x4_v* pv = (const f32x4_v*)(basis + (size_t)v * WELEM);
        #pragma unroll
        for (int i = 0; i < 8; ++i)
          acc[i] += cv * pv[base4 + i * 256];
      }
      #pragma unroll
      for (int i = 0; i < 8; ++i) {
        u16x4 u;
        #pragma unroll
        for (int j = 0; j < 4; ++j) u[j] = f2bf(acc[i][j]);
        ((u16x4*)outp)[base4 + i * 256] = u;
      }
    } else {
      const int n4 = NTOK * DMODEL / 4;
      const int stride = 512 * 256;
      for (int i = (bid - 1024) * 256 + t; i < n4; i += stride) {
        f32x4_v v = ((const f32x4_v*)inputs)[i];
        u16x4 u;
        #pragma unroll
        for (int j = 0; j < 4; ++j) u[j] = f2bf(v[j]);
        ((u16x4*)A_bf)[i] = u;
      }
    }
  }
}

// ---------------------------------------------------------------------------
// bf16 transpose: out[Y][X] = in[X][Y]. 64x64 tile, coalesced both sides.
// 256 threads: each thread covers 2 rows (rr=0,1) on BOTH load and store
// (R8 bug: only 32 of 64 rows were processed).
// ---------------------------------------------------------------------------
__global__ __launch_bounds__(256)
void tr_kernel(const unsigned short* __restrict__ in,
               unsigned short* __restrict__ out, int X, int Y)
{
  __shared__ unsigned short lds[64][72];
  const int ytiles = Y >> 6;
  const int bx = blockIdx.x / ytiles;
  const int by = blockIdx.x % ytiles;
  const int x0 = bx << 6, y0 = by << 6;
  const int t = threadIdx.x;
  const int r0 = t >> 3, c8 = (t & 7) * 8;

  #pragma unroll
  for (int rr = 0; rr < 2; ++rr) {
    const int r = r0 + rr * 32;
    u16x8 v = *(const u16x8*)(in + (size_t)(x0 + r) * Y + y0 + c8);
    #pragma unroll
    for (int j = 0; j < 8; ++j) lds[r][c8 + j] = v[j];
  }
  __syncthreads();
  #pragma unroll
  for (int rr = 0; rr < 2; ++rr) {
    const int r = r0 + rr * 32;
    u16x8 o;
    #pragma unroll
    for (int j = 0; j < 8; ++j) o[j] = lds[c8 + j][r];
    *(u16x8*)(out + (size_t)(y0 + r) * X + x0 + c8) = o;
  }
}

// ---------------------------------------------------------------------------
// 8-wave deep-pipelined GEMM (R5 structure) + REP for counter visibility.
// acc re-zeroed per rep; C written every rep (bit-identical, deterministic).
// ---------------------------------------------------------------------------
template<int BM, int BN, int CHM, int CHN, int EPI, int REP>
__global__ __launch_bounds__(512)
void gemm8p(const unsigned short* __restrict__ A,
            const unsigned short* __restrict__ Bt,
            unsigned short* __restrict__ Cbf,
            float* __restrict__ Cf,
            const float* __restrict__ bias,
            const int* __restrict__ eidx_p,
            int M, int N, int K)
{
  constexpr int BK   = 32;
  constexpr int FM   = BM / 32;
  constexpr int FN   = BN / 64;
  constexpr int P    = (FM * FN) / 16;
  constexpr int SLOT = (BM + BN) * BK * 2;
  constexpr int L    = SLOT / 16 / 512;
  constexpr int LPP  = L / P;
  constexpr int ACH  = BM * 4;
  constexpr int JA   = ACH / 512;

  __shared__ __align__(16) char smem[4 * SLOT];

  const int nb  = N / BN;
  const int ncn = nb / CHN;
  const int xcd = blockIdx.x & 7;
  const int idx = blockIdx.x >> 3;
  const int bm  = (xcd / ncn) * CHM + idx / CHN;
  const int bn  = (xcd % ncn) * CHN + idx % CHN;
  const int m0 = bm * BM, n0 = bn * BN;

  const int tid = threadIdx.x;
  const int w = tid >> 6, l = tid & 63;
  const int wm = w >> 2, wn = w & 3;
  const int lrow = l & 15, lkc = l >> 4;

  uint32_t soff[L];
  #pragma unroll
  for (int j = 0; j < L; ++j) {
    const int q = tid + j * 512;
    if (j < JA) {
      const int r = q >> 2, cs = (q & 3) ^ ((r >> 1) & 3);
      soff[j] = (uint32_t)(m0 + r) * (uint32_t)K + cs * 8;
    } else {
      const int q2 = q - ACH;
      const int r = q2 >> 2, cs = (q2 & 3) ^ ((r >> 1) & 3);
      soff[j] = (uint32_t)(n0 + r) * (uint32_t)K + cs * 8;
    }
  }

  int aoff[FM], boff[FN];
  #pragma unroll
  for (int f = 0; f < FM; ++f) {
    const int r = wm * (BM / 2) + f * 16 + lrow;
    aoff[f] = r * 64 + ((lkc ^ ((r >> 1) & 3)) << 4);
  }
  #pragma unroll
  for (int n_ = 0; n_ < FN; ++n_) {
    const int r = wn * (BN / 4) + n_ * 16 + lrow;
    boff[n_] = BM * 64 + r * 64 + ((lkc ^ ((r >> 1) & 3)) << 4);
  }

  const int NT = K / BK;
  f32x4_v acc[FM][FN];
  bf16x8 bfr[FN];

  for (int rep = 0; rep < REP; ++rep) {
    #pragma unroll
    for (int f = 0; f < FM; ++f)
      #pragma unroll
      for (int n_ = 0; n_ < FN; ++n_) acc[f][n_] = (f32x4_v){0.f, 0.f, 0.f, 0.f};

    for (int tt = 0; tt < 3; ++tt) {
      char* sb = smem + tt * SLOT;
      #pragma unroll
      for (int j = 0; j < L; ++j)
        gload16((j < JA ? A : Bt) + soff[j] + tt * BK,
                (unsigned short*)(sb + (tid + j * 512) * 16));
    }
    if constexpr (L == 4) { VMCNT(8); } else { VMCNT(6); }
    __builtin_amdgcn_s_barrier();
    __builtin_amdgcn_sched_barrier(0);

    for (int t = 0; t < NT; ++t) {
      const char* sb = smem + (t & 3) * SLOT;
      char* pb = smem + ((t + 3) & 3) * SLOT;
      const bool do_stage = (t + 3 < NT);
      #pragma unroll
      for (int p = 0; p < P; ++p) {
        bf16x8 af[4];
        #pragma unroll
        for (int m_ = 0; m_ < 4; ++m_)
          af[m_] = *(const bf16x8*)(sb + aoff[p * 4 + m_]);
        if (p == 0) {
          #pragma unroll
          for (int n_ = 0; n_ < FN; ++n_)
            bfr[n_] = *(const bf16x8*)(sb + boff[n_]);
        }
        if (do_stage) {
          #pragma unroll
          for (int jj = 0; jj < LPP; ++jj) {
            const int j = p * LPP + jj;
            gload16((j < JA ? A : Bt) + soff[j] + (t + 3) * BK,
                    (unsigned short*)(pb + (tid + j * 512) * 16));
          }
        }
        __builtin_amdgcn_s_barrier();
        __builtin_amdgcn_s_setprio(1);
        #pragma unroll
        for (int m_ = 0; m_ < 4; ++m_)
          #pragma unroll
          for (int n_ = 0; n_ < FN; ++n_)
            acc[p * 4 + m_][n_] = __builtin_amdgcn_mfma_f32_16x16x32_bf16(
                af[m_], bfr[n_], acc[p * 4 + m_][n_], 0, 0, 0);
        __builtin_amdgcn_s_setprio(0);
        if (p == P - 1) {
          if (t < NT - 3)       { if constexpr (L == 4) { VMCNT(8); } else { VMCNT(6); } }
          else if (t == NT - 3) { if constexpr (L == 4) { VMCNT(4); } else { VMCNT(3); } }
          else if (t == NT - 2) { VMCNT(0); }
        }
        __builtin_amdgcn_s_barrier();
        __builtin_amdgcn_sched_barrier(0);
      }
    }

    const int colq = l & 15;
    const int rowq = (l >> 4) * 4;
    if constexpr (EPI == 0) {
      #pragma unroll
      for (int f = 0; f < FM; ++f)
        #pragma unroll
        for (int n_ = 0; n_ < FN; ++n_) {
          const int col = n0 + wn * (BN / 4) + n_ * 16 + colq;
          #pragma unroll
          for (int r = 0; r < 4; ++r) {
            const int row = m0 + wm * (BM / 2) + f * 16 + rowq + r;
            Cbf[(size_t)row * N + col] = f2bf(gelu_fast(acc[f][n_][r]));
          }
        }
    } else {
      const int e = *eidx_p;
      const float* brow = bias + (size_t)e * N;
      #pragma unroll
      for (int n_ = 0; n_ < FN; ++n_) {
        const int col = n0 + wn * (BN / 4) + n_ * 16 + colq;
        const float bv = brow[col];
        #pragma unroll
        for (int f = 0; f < FM; ++f)
          #pragma unroll
          for (int r = 0; r < 4; ++r) {
            const int row = m0 + wm * (BM / 2) + f * 16 + rowq + r;
            Cf[(size_t)row * N + col] = acc[f][n_][r] + bv;
          }
      }
    }
  }
}

// ---------------------------------------------------------------------------
// MEASUREMENT ROUND (take 2): wrec x3, gemm1 x4 -> visible in top-5 counters.
// ws layout (96 MB): A_bf 0-16 | hidden 16-80 (overlays dead nat bufs)
//   nat_up 16-24, nat_dn 24-32 (dead after transposes) | WupT 80-88 | WdnT 88-96.
// ---------------------------------------------------------------------------
extern "C" void kernel_launch(void* const* d_in, const int* in_sizes, int n_in,
                              void* d_out, int out_size, void* d_ws, size_t ws_size,
                              hipStream_t stream)
{
  const float* inputs     = (const float*)d_in[0];
  const float* basis_up   = (const float*)d_in[1];
  const float* basis_down = (const float*)d_in[2];
  const float* cup        = (const float*)d_in[3];
  const float* cdn        = (const float*)d_in[4];
  const float* bias       = (const float*)d_in[5];
  const int*   eidx       = (const int*)d_in[6];
  float*       out        = (float*)d_out;

  char* ws = (char*)d_ws;
  unsigned short* A_bf    = (unsigned short*)(ws);
  unsigned short* nat_up  = (unsigned short*)(ws + (16u << 20));
  unsigned short* nat_dn  = (unsigned short*)(ws + (24u << 20));
  unsigned short* hidden  = (unsigned short*)(ws + (16u << 20));  // overlays nats (dead)
  unsigned short* WupT    = (unsigned short*)(ws + (80u << 20));
  unsigned short* WdnT    = (unsigned short*)(ws + (88u << 20));

  // streaming reconstruct (natural layout) + cvt   [x3 for counters]
  wrec_kernel<3><<<1536, 256, 0, stream>>>(
      inputs, basis_up, basis_down, cup, cdn, eidx, A_bf, nat_up, nat_dn);

  // transposes: WupT[h][d] <- nat_up[d][h]; WdnT[d][h] <- nat_dn[h][d]
  tr_kernel<<<1024, 256, 0, stream>>>(nat_up, WupT, DMODEL, HDDIM);
  tr_kernel<<<1024, 256, 0, stream>>>(nat_dn, WdnT, HDDIM, DMODEL);

  // hidden = gelu(A_bf @ WupT^T)   [x4 for counters]
  gemm8p<256, 256, 8, 8, 0, 4><<<512, 512, 0, stream>>>(
      A_bf, WupT, hidden, nullptr, nullptr, nullptr, NTOK, HDDIM, DMODEL);

  // out = hidden @ WdnT^T + bias
  gemm8p<128, 256, 8, 4, 1, 1><<<256, 512, 0, stream>>>(
      hidden, WdnT, nullptr, out, bias, eidx, NTOK, DMODEL, HDDIM);
}

// Round 10
// 442.483 us; speedup vs baseline: 2.3334x; 2.3334x over previous
//
#include <hip/hip_runtime.h>
#include <cstdint>

#define NTOK 8192
#define DMODEL 1024
#define HDDIM 4096
#define NVEC 32

typedef float f32x4_v __attribute__((ext_vector_type(4)));
typedef __bf16 bf16x8 __attribute__((ext_vector_type(8)));
typedef unsigned short u16x4 __attribute__((ext_vector_type(4)));
typedef unsigned short u16x8 __attribute__((ext_vector_type(8)));

__device__ __forceinline__ unsigned short f2bf(float f) {
  union { float f; uint32_t u; } x; x.f = f;
  uint32_t r = (x.u + 0x7FFFu + ((x.u >> 16) & 1u)) >> 16;
  return (unsigned short)r;
}

__device__ __forceinline__ float gelu_fast(float x) {
  float t = x * x;
  float z = x * (2.3022082f + 0.1029440f * t);
  float e = exp2f(-z);
  return x / (1.0f + e);
}

#define VMCNT(n) asm volatile("s_waitcnt vmcnt(" #n ")" ::: "memory")

__device__ __forceinline__ void gload16(const unsigned short* g, unsigned short* lds)
{
  __builtin_amdgcn_global_load_lds((__attribute__((address_space(1))) void*)g,
                                   (__attribute__((address_space(3))) void*)lds,
                                   16, 0, 0);
}

// ---------------------------------------------------------------------------
// Reconstruct + transpose (R7 version, measured ~224us total in mem_kernel):
// tile = 16 rows x 256 cols; wave reads 1KB contiguous per row-segment.
// outT[y][x] (bf16, ld=X) = sum_v c[v]*basis[v][x][y]
// ---------------------------------------------------------------------------
__device__ __forceinline__
void reconstruct_body(const float* __restrict__ basis,
                      const float* __restrict__ coeffs,
                      int e, unsigned short* __restrict__ outT,
                      int X, int Y, int tile, int bid, char* smem)
{
  float (*lds)[260] = (float (*)[260])smem;
  const int xtiles = X >> 4;
  const int bx = tile % xtiles;
  const int by = tile / xtiles;
  const int x0 = bx << 4, y0 = by << 8;
  const int t  = threadIdx.x;
  const int w  = t >> 6, l = t & 63;

  f32x4_v acc[4];
  #pragma unroll
  for (int i = 0; i < 4; ++i) acc[i] = (f32x4_v){0.f, 0.f, 0.f, 0.f};

  const size_t mat = (size_t)X * (size_t)Y;
  uint32_t roff[4];
  #pragma unroll
  for (int i = 0; i < 4; ++i)
    roff[i] = (uint32_t)(x0 + w * 4 + i) * (uint32_t)Y + (uint32_t)(y0 + l * 4);

  #pragma unroll 2
  for (int vv = 0; vv < NVEC; ++vv) {
    const int v = (vv + bid) & (NVEC - 1);
    const float cv = coeffs[e * NVEC + v];
    const float* pv = basis + (size_t)v * mat;
    #pragma unroll
    for (int i = 0; i < 4; ++i) {
      f32x4_v d = *(const f32x4_v*)(pv + roff[i]);
      acc[i] += cv * d;
    }
  }

  #pragma unroll
  for (int i = 0; i < 4; ++i)
    *(f32x4_v*)&lds[w * 4 + i][l * 4] = acc[i];
  __syncthreads();

  const int y = y0 + t;
  u16x8 o0, o1;
  #pragma unroll
  for (int x = 0; x < 8; ++x)  o0[x] = f2bf(lds[x][t]);
  #pragma unroll
  for (int x = 0; x < 8; ++x)  o1[x] = f2bf(lds[8 + x][t]);
  unsigned short* dst = outT + (size_t)y * X + x0;
  *(u16x8*)dst = o0;
  *(u16x8*)(dst + 8) = o1;
}

// ---------------------------------------------------------------------------
// Merged memory kernel: rec_up (0..1023) | rec_dn (1024..2047) | cvt (2048..2559)
// ---------------------------------------------------------------------------
#define CVT_BLKS 512

__global__ __launch_bounds__(256)
void mem_kernel(const float* __restrict__ inputs,
                const float* __restrict__ basis_up,
                const float* __restrict__ basis_down,
                const float* __restrict__ cup,
                const float* __restrict__ cdn,
                const int* __restrict__ eidx_p,
                unsigned short* __restrict__ A_bf,
                unsigned short* __restrict__ WupT,
                unsigned short* __restrict__ WdnT)
{
  __shared__ __align__(16) char smem[16 * 260 * 4];
  const int bid = blockIdx.x;
  if (bid < 1024) {
    reconstruct_body(basis_up, cup, *eidx_p, WupT, DMODEL, HDDIM, bid, bid, smem);
  } else if (bid < 2048) {
    reconstruct_body(basis_down, cdn, *eidx_p, WdnT, HDDIM, DMODEL, bid - 1024, bid, smem);
  } else {
    const int n4 = NTOK * DMODEL / 4;
    const int stride = CVT_BLKS * 256;
    for (int i = (bid - 2048) * 256 + threadIdx.x; i < n4; i += stride) {
      f32x4_v v = ((const f32x4_v*)inputs)[i];
      u16x4 u;
      #pragma unroll
      for (int j = 0; j < 4; ++j) u[j] = f2bf(v[j]);
      ((u16x4*)A_bf)[i] = u;
    }
  }
}

// ---------------------------------------------------------------------------
// init_out: out[r][c] = bias[e][c]  (f32). g2 then atomically accumulates.
// ---------------------------------------------------------------------------
__global__ __launch_bounds__(256)
void init_out(float* __restrict__ out, const float* __restrict__ bias,
              const int* __restrict__ eidx_p)
{
  const int e = *eidx_p;
  const f32x4_v* b4 = (const f32x4_v*)(bias + (size_t)e * DMODEL);
  f32x4_v* o4 = (f32x4_v*)out;
  const int i = blockIdx.x * 256 + threadIdx.x;   // grid 2048 -> 524288 threads
  #pragma unroll
  for (int k = 0; k < 4; ++k) {
    const int idx = i + k * 524288;
    o4[idx] = b4[idx & 255];
  }
}

// ---------------------------------------------------------------------------
// 8-wave deep-pipelined GEMM, BK=32, 4-slot LDS ring, lead-3 counted vmcnt.
// KSPLIT: grid = tiles*KSPLIT; each split handles K/KSPLIT (soff pre-offset).
// EPI==0: C = gelu(acc) -> bf16.   EPI==2: atomicAdd(Cf, acc) (f32, 2 adds
// per element across splits -> commutative -> deterministic).
// ---------------------------------------------------------------------------
template<int BM, int BN, int CHM, int CHN, int EPI, int KSPLIT>
__global__ __launch_bounds__(512)
void gemm8p(const unsigned short* __restrict__ A,
            const unsigned short* __restrict__ Bt,
            unsigned short* __restrict__ Cbf,
            float* __restrict__ Cf,
            int M, int N, int K)
{
  constexpr int BK   = 32;
  constexpr int FM   = BM / 32;
  constexpr int FN   = BN / 64;
  constexpr int P    = (FM * FN) / 16;
  constexpr int SLOT = (BM + BN) * BK * 2;
  constexpr int L    = SLOT / 16 / 512;
  constexpr int LPP  = L / P;
  constexpr int ACH  = BM * 4;
  constexpr int JA   = ACH / 512;

  __shared__ __align__(16) char smem[4 * SLOT];

  // split index + tile index
  int bid = blockIdx.x;
  int ks = 0;
  if constexpr (KSPLIT > 1) {
    const int tiles = gridDim.x / KSPLIT;
    ks = bid / tiles;
    bid -= ks * tiles;
  }
  const int ksub = K / KSPLIT;
  const uint32_t kbeg = (uint32_t)ks * (uint32_t)ksub;

  const int nb  = N / BN;
  const int ncn = nb / CHN;
  const int xcd = bid & 7;
  const int idx = bid >> 3;
  const int bm  = (xcd / ncn) * CHM + idx / CHN;
  const int bn  = (xcd % ncn) * CHN + idx % CHN;
  const int m0 = bm * BM, n0 = bn * BN;

  const int tid = threadIdx.x;
  const int w = tid >> 6, l = tid & 63;
  const int wm = w >> 2, wn = w & 3;
  const int lrow = l & 15, lkc = l >> 4;

  uint32_t soff[L];
  #pragma unroll
  for (int j = 0; j < L; ++j) {
    const int q = tid + j * 512;
    if (j < JA) {
      const int r = q >> 2, cs = (q & 3) ^ ((r >> 1) & 3);
      soff[j] = (uint32_t)(m0 + r) * (uint32_t)K + cs * 8 + kbeg;
    } else {
      const int q2 = q - ACH;
      const int r = q2 >> 2, cs = (q2 & 3) ^ ((r >> 1) & 3);
      soff[j] = (uint32_t)(n0 + r) * (uint32_t)K + cs * 8 + kbeg;
    }
  }

  int aoff[FM], boff[FN];
  #pragma unroll
  for (int f = 0; f < FM; ++f) {
    const int r = wm * (BM / 2) + f * 16 + lrow;
    aoff[f] = r * 64 + ((lkc ^ ((r >> 1) & 3)) << 4);
  }
  #pragma unroll
  for (int n_ = 0; n_ < FN; ++n_) {
    const int r = wn * (BN / 4) + n_ * 16 + lrow;
    boff[n_] = BM * 64 + r * 64 + ((lkc ^ ((r >> 1) & 3)) << 4);
  }

  f32x4_v acc[FM][FN];
  #pragma unroll
  for (int f = 0; f < FM; ++f)
    #pragma unroll
    for (int n_ = 0; n_ < FN; ++n_) acc[f][n_] = (f32x4_v){0.f, 0.f, 0.f, 0.f};

  const int NT = ksub / BK;

  for (int tt = 0; tt < 3; ++tt) {
    char* sb = smem + tt * SLOT;
    #pragma unroll
    for (int j = 0; j < L; ++j)
      gload16((j < JA ? A : Bt) + soff[j] + tt * BK,
              (unsigned short*)(sb + (tid + j * 512) * 16));
  }
  if constexpr (L == 4) { VMCNT(8); } else { VMCNT(6); }
  __builtin_amdgcn_s_barrier();
  __builtin_amdgcn_sched_barrier(0);

  bf16x8 bfr[FN];
  for (int t = 0; t < NT; ++t) {
    const char* sb = smem + (t & 3) * SLOT;
    char* pb = smem + ((t + 3) & 3) * SLOT;
    const bool do_stage = (t + 3 < NT);
    #pragma unroll
    for (int p = 0; p < P; ++p) {
      bf16x8 af[4];
      #pragma unroll
      for (int m_ = 0; m_ < 4; ++m_)
        af[m_] = *(const bf16x8*)(sb + aoff[p * 4 + m_]);
      if (p == 0) {
        #pragma unroll
        for (int n_ = 0; n_ < FN; ++n_)
          bfr[n_] = *(const bf16x8*)(sb + boff[n_]);
      }
      if (do_stage) {
        #pragma unroll
        for (int jj = 0; jj < LPP; ++jj) {
          const int j = p * LPP + jj;
          gload16((j < JA ? A : Bt) + soff[j] + (t + 3) * BK,
                  (unsigned short*)(pb + (tid + j * 512) * 16));
        }
      }
      __builtin_amdgcn_s_barrier();
      __builtin_amdgcn_s_setprio(1);
      #pragma unroll
      for (int m_ = 0; m_ < 4; ++m_)
        #pragma unroll
        for (int n_ = 0; n_ < FN; ++n_)
          acc[p * 4 + m_][n_] = __builtin_amdgcn_mfma_f32_16x16x32_bf16(
              af[m_], bfr[n_], acc[p * 4 + m_][n_], 0, 0, 0);
      __builtin_amdgcn_s_setprio(0);
      if (p == P - 1) {
        if (t < NT - 3)       { if constexpr (L == 4) { VMCNT(8); } else { VMCNT(6); } }
        else if (t == NT - 3) { if constexpr (L == 4) { VMCNT(4); } else { VMCNT(3); } }
        else if (t == NT - 2) { VMCNT(0); }
      }
      __builtin_amdgcn_s_barrier();
      __builtin_amdgcn_sched_barrier(0);
    }
  }

  const int colq = l & 15;
  const int rowq = (l >> 4) * 4;
  if constexpr (EPI == 0) {
    #pragma unroll
    for (int f = 0; f < FM; ++f)
      #pragma unroll
      for (int n_ = 0; n_ < FN; ++n_) {
        const int col = n0 + wn * (BN / 4) + n_ * 16 + colq;
        #pragma unroll
        for (int r = 0; r < 4; ++r) {
          const int row = m0 + wm * (BM / 2) + f * 16 + rowq + r;
          Cbf[(size_t)row * N + col] = f2bf(gelu_fast(acc[f][n_][r]));
        }
      }
  } else {
    #pragma unroll
    for (int n_ = 0; n_ < FN; ++n_) {
      const int col = n0 + wn * (BN / 4) + n_ * 16 + colq;
      #pragma unroll
      for (int f = 0; f < FM; ++f)
        #pragma unroll
        for (int r = 0; r < 4; ++r) {
          const int row = m0 + wm * (BM / 2) + f * 16 + rowq + r;
          atomicAdd(&Cf[(size_t)row * N + col], acc[f][n_][r]);
        }
    }
  }
}

// ---------------------------------------------------------------------------
extern "C" void kernel_launch(void* const* d_in, const int* in_sizes, int n_in,
                              void* d_out, int out_size, void* d_ws, size_t ws_size,
                              hipStream_t stream)
{
  const float* inputs     = (const float*)d_in[0];
  const float* basis_up   = (const float*)d_in[1];
  const float* basis_down = (const float*)d_in[2];
  const float* cup        = (const float*)d_in[3];
  const float* cdn        = (const float*)d_in[4];
  const float* bias       = (const float*)d_in[5];
  const int*   eidx       = (const int*)d_in[6];
  float*       out        = (float*)d_out;

  char* ws = (char*)d_ws;
  unsigned short* A_bf   = (unsigned short*)(ws);                  // 16 MB
  unsigned short* hidden = (unsigned short*)(ws + (16u << 20));    // 64 MB
  unsigned short* WupT   = (unsigned short*)(ws + (80u << 20));    //  8 MB
  unsigned short* WdnT   = (unsigned short*)(ws + (88u << 20));    //  8 MB

  // fused reconstruct(+transpose) + cvt  (~224 us, structural ceiling ~4.9 TB/s)
  mem_kernel<<<2560, 256, 0, stream>>>(
      inputs, basis_up, basis_down, cup, cdn, eidx, A_bf, WupT, WdnT);

  // out = bias (f32), then g2 accumulates atomically
  init_out<<<2048, 256, 0, stream>>>(out, bias, eidx);

  // hidden = gelu(A_bf @ WupT^T)   M=8192 N=4096 K=1024; grid 512
  gemm8p<256, 256, 8, 8, 0, 1><<<512, 512, 0, stream>>>(
      A_bf, WupT, hidden, nullptr, NTOK, HDDIM, DMODEL);

  // out += hidden @ WdnT^T   K-split x2: grid 512 (256 tiles x 2 K-halves)
  gemm8p<128, 256, 8, 4, 2, 2><<<512, 512, 0, stream>>>(
      hidden, WdnT, nullptr, out, NTOK, DMODEL, HDDIM);
}

// Round 11
// 353.364 us; speedup vs baseline: 2.9218x; 1.2522x over previous
//
#include <hip/hip_runtime.h>
#include <cstdint>

#define NTOK 8192
#define DMODEL 1024
#define HDDIM 4096
#define NVEC 32

typedef float f32x4_v __attribute__((ext_vector_type(4)));
typedef __bf16 bf16x8 __attribute__((ext_vector_type(8)));
typedef unsigned short u16x4 __attribute__((ext_vector_type(4)));
typedef unsigned short u16x8 __attribute__((ext_vector_type(8)));

__device__ __forceinline__ unsigned short f2bf(float f) {
  union { float f; uint32_t u; } x; x.f = f;
  uint32_t r = (x.u + 0x7FFFu + ((x.u >> 16) & 1u)) >> 16;
  return (unsigned short)r;
}

__device__ __forceinline__ float gelu_fast(float x) {
  float t = x * x;
  float z = x * (2.3022082f + 0.1029440f * t);
  float e = exp2f(-z);
  return x / (1.0f + e);
}

#define VMCNT(n) asm volatile("s_waitcnt vmcnt(" #n ")" ::: "memory")

__device__ __forceinline__ void gload16(const unsigned short* g, unsigned short* lds)
{
  __builtin_amdgcn_global_load_lds((__attribute__((address_space(1))) void*)g,
                                   (__attribute__((address_space(3))) void*)lds,
                                   16, 0, 0);
}

// ---------------------------------------------------------------------------
// Reconstruct + transpose (R7 structure): tile 16 rows x 256 cols; wave reads
// 1KB contiguous per row-segment. unroll 4 (32 loads hoistable) + nontemporal
// loads on the read-once basis stream.
// outT[y][x] (bf16, ld=X) = sum_v c[v]*basis[v][x][y]
// ---------------------------------------------------------------------------
__device__ __forceinline__
void reconstruct_body(const float* __restrict__ basis,
                      const float* __restrict__ coeffs,
                      int e, unsigned short* __restrict__ outT,
                      int X, int Y, int tile, int bid, char* smem)
{
  float (*lds)[260] = (float (*)[260])smem;
  const int xtiles = X >> 4;
  const int bx = tile % xtiles;
  const int by = tile / xtiles;
  const int x0 = bx << 4, y0 = by << 8;
  const int t  = threadIdx.x;
  const int w  = t >> 6, l = t & 63;

  f32x4_v acc[4];
  #pragma unroll
  for (int i = 0; i < 4; ++i) acc[i] = (f32x4_v){0.f, 0.f, 0.f, 0.f};

  const size_t mat = (size_t)X * (size_t)Y;
  uint32_t roff[4];
  #pragma unroll
  for (int i = 0; i < 4; ++i)
    roff[i] = (uint32_t)(x0 + w * 4 + i) * (uint32_t)Y + (uint32_t)(y0 + l * 4);

  #pragma unroll 4
  for (int vv = 0; vv < NVEC; ++vv) {
    const int v = (vv + bid) & (NVEC - 1);
    const float cv = coeffs[e * NVEC + v];
    const float* pv = basis + (size_t)v * mat;
    #pragma unroll
    for (int i = 0; i < 4; ++i) {
      f32x4_v d = __builtin_nontemporal_load((const f32x4_v*)(pv + roff[i]));
      acc[i] += cv * d;
    }
  }

  #pragma unroll
  for (int i = 0; i < 4; ++i)
    *(f32x4_v*)&lds[w * 4 + i][l * 4] = acc[i];
  __syncthreads();

  const int y = y0 + t;
  u16x8 o0, o1;
  #pragma unroll
  for (int x = 0; x < 8; ++x)  o0[x] = f2bf(lds[x][t]);
  #pragma unroll
  for (int x = 0; x < 8; ++x)  o1[x] = f2bf(lds[8 + x][t]);
  unsigned short* dst = outT + (size_t)y * X + x0;
  *(u16x8*)dst = o0;
  *(u16x8*)(dst + 8) = o1;
}

// ---------------------------------------------------------------------------
// Merged memory kernel: rec_up (0..1023) | rec_dn (1024..2047) | cvt (2048..2559)
// ---------------------------------------------------------------------------
#define CVT_BLKS 512

__global__ __launch_bounds__(256)
void mem_kernel(const float* __restrict__ inputs,
                const float* __restrict__ basis_up,
                const float* __restrict__ basis_down,
                const float* __restrict__ cup,
                const float* __restrict__ cdn,
                const int* __restrict__ eidx_p,
                unsigned short* __restrict__ A_bf,
                unsigned short* __restrict__ WupT,
                unsigned short* __restrict__ WdnT)
{
  __shared__ __align__(16) char smem[16 * 260 * 4];
  const int bid = blockIdx.x;
  if (bid < 1024) {
    reconstruct_body(basis_up, cup, *eidx_p, WupT, DMODEL, HDDIM, bid, bid, smem);
  } else if (bid < 2048) {
    reconstruct_body(basis_down, cdn, *eidx_p, WdnT, HDDIM, DMODEL, bid - 1024, bid, smem);
  } else {
    const int n4 = NTOK * DMODEL / 4;
    const int stride = CVT_BLKS * 256;
    for (int i = (bid - 2048) * 256 + threadIdx.x; i < n4; i += stride) {
      f32x4_v v = ((const f32x4_v*)inputs)[i];
      u16x4 u;
      #pragma unroll
      for (int j = 0; j < 4; ++j) u[j] = f2bf(v[j]);
      ((u16x4*)A_bf)[i] = u;
    }
  }
}

// ---------------------------------------------------------------------------
// g1: 8-wave BK=32, 4-slot ring, lead-3 counted vmcnt (R5/R7 proven, 1.35 PF)
// ---------------------------------------------------------------------------
template<int BM, int BN, int CHM, int CHN>
__global__ __launch_bounds__(512)
void gemm8p(const unsigned short* __restrict__ A,
            const unsigned short* __restrict__ Bt,
            unsigned short* __restrict__ Cbf,
            int M, int N, int K)
{
  constexpr int BK   = 32;
  constexpr int FM   = BM / 32;
  constexpr int FN   = BN / 64;
  constexpr int P    = (FM * FN) / 16;
  constexpr int SLOT = (BM + BN) * BK * 2;
  constexpr int L    = SLOT / 16 / 512;
  constexpr int LPP  = L / P;
  constexpr int ACH  = BM * 4;
  constexpr int JA   = ACH / 512;

  __shared__ __align__(16) char smem[4 * SLOT];

  const int nb  = N / BN;
  const int ncn = nb / CHN;
  const int xcd = blockIdx.x & 7;
  const int idx = blockIdx.x >> 3;
  const int bm  = (xcd / ncn) * CHM + idx / CHN;
  const int bn  = (xcd % ncn) * CHN + idx % CHN;
  const int m0 = bm * BM, n0 = bn * BN;

  const int tid = threadIdx.x;
  const int w = tid >> 6, l = tid & 63;
  const int wm = w >> 2, wn = w & 3;
  const int lrow = l & 15, lkc = l >> 4;

  uint32_t soff[L];
  #pragma unroll
  for (int j = 0; j < L; ++j) {
    const int q = tid + j * 512;
    if (j < JA) {
      const int r = q >> 2, cs = (q & 3) ^ ((r >> 1) & 3);
      soff[j] = (uint32_t)(m0 + r) * (uint32_t)K + cs * 8;
    } else {
      const int q2 = q - ACH;
      const int r = q2 >> 2, cs = (q2 & 3) ^ ((r >> 1) & 3);
      soff[j] = (uint32_t)(n0 + r) * (uint32_t)K + cs * 8;
    }
  }

  int aoff[FM], boff[FN];
  #pragma unroll
  for (int f = 0; f < FM; ++f) {
    const int r = wm * (BM / 2) + f * 16 + lrow;
    aoff[f] = r * 64 + ((lkc ^ ((r >> 1) & 3)) << 4);
  }
  #pragma unroll
  for (int n_ = 0; n_ < FN; ++n_) {
    const int r = wn * (BN / 4) + n_ * 16 + lrow;
    boff[n_] = BM * 64 + r * 64 + ((lkc ^ ((r >> 1) & 3)) << 4);
  }

  f32x4_v acc[FM][FN];
  #pragma unroll
  for (int f = 0; f < FM; ++f)
    #pragma unroll
    for (int n_ = 0; n_ < FN; ++n_) acc[f][n_] = (f32x4_v){0.f, 0.f, 0.f, 0.f};

  const int NT = K / BK;

  for (int tt = 0; tt < 3; ++tt) {
    char* sb = smem + tt * SLOT;
    #pragma unroll
    for (int j = 0; j < L; ++j)
      gload16((j < JA ? A : Bt) + soff[j] + tt * BK,
              (unsigned short*)(sb + (tid + j * 512) * 16));
  }
  VMCNT(8);
  __builtin_amdgcn_s_barrier();
  __builtin_amdgcn_sched_barrier(0);

  bf16x8 bfr[FN];
  for (int t = 0; t < NT; ++t) {
    const char* sb = smem + (t & 3) * SLOT;
    char* pb = smem + ((t + 3) & 3) * SLOT;
    const bool do_stage = (t + 3 < NT);
    #pragma unroll
    for (int p = 0; p < P; ++p) {
      bf16x8 af[4];
      #pragma unroll
      for (int m_ = 0; m_ < 4; ++m_)
        af[m_] = *(const bf16x8*)(sb + aoff[p * 4 + m_]);
      if (p == 0) {
        #pragma unroll
        for (int n_ = 0; n_ < FN; ++n_)
          bfr[n_] = *(const bf16x8*)(sb + boff[n_]);
      }
      if (do_stage) {
        #pragma unroll
        for (int jj = 0; jj < LPP; ++jj) {
          const int j = p * LPP + jj;
          gload16((j < JA ? A : Bt) + soff[j] + (t + 3) * BK,
                  (unsigned short*)(pb + (tid + j * 512) * 16));
        }
      }
      __builtin_amdgcn_s_barrier();
      __builtin_amdgcn_s_setprio(1);
      #pragma unroll
      for (int m_ = 0; m_ < 4; ++m_)
        #pragma unroll
        for (int n_ = 0; n_ < FN; ++n_)
          acc[p * 4 + m_][n_] = __builtin_amdgcn_mfma_f32_16x16x32_bf16(
              af[m_], bfr[n_], acc[p * 4 + m_][n_], 0, 0, 0);
      __builtin_amdgcn_s_setprio(0);
      if (p == P - 1) {
        if (t < NT - 3)       { VMCNT(8); }
        else if (t == NT - 3) { VMCNT(4); }
        else if (t == NT - 2) { VMCNT(0); }
      }
      __builtin_amdgcn_s_barrier();
      __builtin_amdgcn_sched_barrier(0);
    }
  }

  const int colq = l & 15;
  const int rowq = (l >> 4) * 4;
  #pragma unroll
  for (int f = 0; f < FM; ++f)
    #pragma unroll
    for (int n_ = 0; n_ < FN; ++n_) {
      const int col = n0 + wn * (BN / 4) + n_ * 16 + colq;
      #pragma unroll
      for (int r = 0; r < 4; ++r) {
        const int row = m0 + wm * (BM / 2) + f * 16 + rowq + r;
        Cbf[(size_t)row * N + col] = f2bf(gelu_fast(acc[f][n_][r]));
      }
    }
}

// ---------------------------------------------------------------------------
// g2: BM=128 BN=256 BK=64, 3-slot ring (144KB LDS), lead-2, P=2 kk-phases.
// Swizzle: 8 chunks/row, chunk' = chunk ^ (r&7) (2-way banks, involution).
// Epilogue: out = acc + bias.
// ---------------------------------------------------------------------------
template<int CHM, int CHN>
__global__ __launch_bounds__(512)
void gemm_k64(const unsigned short* __restrict__ A,
              const unsigned short* __restrict__ Bt,
              float* __restrict__ Cf,
              const float* __restrict__ bias,
              const int* __restrict__ eidx_p,
              int M, int N, int K)
{
  constexpr int BM = 128, BN = 256, BK = 64;
  constexpr int SLOT = (BM + BN) * BK * 2;   // 49152 B
  constexpr int L = 6, JA = 2;               // 3072 chunks/tile / 512 thr
  __shared__ __align__(16) char smem[3 * SLOT];  // 144 KB

  const int nb  = N / BN;
  const int ncn = nb / CHN;
  const int xcd = blockIdx.x & 7;
  const int idx = blockIdx.x >> 3;
  const int bm  = (xcd / ncn) * CHM + idx / CHN;
  const int bn  = (xcd % ncn) * CHN + idx % CHN;
  const int m0 = bm * BM, n0 = bn * BN;

  const int tid = threadIdx.x;
  const int w = tid >> 6, l = tid & 63;
  const int wm = w >> 2, wn = w & 3;
  const int lrow = l & 15, lkc = l >> 4;

  // staging: A chunks q=0..1023 (r=q>>3), B q2=0..2047 (r=q2>>3); 8 chunks/row
  uint32_t soff[L];
  #pragma unroll
  for (int j = 0; j < L; ++j) {
    const int q = tid + j * 512;
    if (j < JA) {
      const int r = q >> 3, cs = (q & 7) ^ (r & 7);
      soff[j] = (uint32_t)(m0 + r) * (uint32_t)K + cs * 8;
    } else {
      const int q2 = q - 1024;
      const int r = q2 >> 3, cs = (q2 & 7) ^ (r & 7);
      soff[j] = (uint32_t)(n0 + r) * (uint32_t)K + cs * 8;
    }
  }

  // fragment bases: row stride 128 B; per-phase chunk = (p*4+lkc)^ (r&7)
  int abase[4], aswz[4], bbase[4], bswz[4];
  #pragma unroll
  for (int f = 0; f < 4; ++f) {
    const int r = wm * 64 + f * 16 + lrow;
    abase[f] = r * 128; aswz[f] = r & 7;
  }
  #pragma unroll
  for (int n_ = 0; n_ < 4; ++n_) {
    const int r = wn * 64 + n_ * 16 + lrow;
    bbase[n_] = 16384 + r * 128; bswz[n_] = r & 7;
  }

  f32x4_v acc[4][4];
  #pragma unroll
  for (int f = 0; f < 4; ++f)
    #pragma unroll
    for (int n_ = 0; n_ < 4; ++n_) acc[f][n_] = (f32x4_v){0.f, 0.f, 0.f, 0.f};

  const int NT = K / BK;   // 64

  // prologue: stage tiles 0,1
  for (int tt = 0; tt < 2; ++tt) {
    char* sb = smem + tt * SLOT;
    #pragma unroll
    for (int j = 0; j < L; ++j)
      gload16((j < JA ? A : Bt) + soff[j] + tt * BK,
              (unsigned short*)(sb + (tid + j * 512) * 16));
  }
  VMCNT(6);   // tile 0 ready (tile 1's 6 in flight)
  __builtin_amdgcn_s_barrier();
  __builtin_amdgcn_sched_barrier(0);

  int cur = 0, pf = 2;
  for (int t = 0; t < NT; ++t) {
    const char* sb = smem + cur * SLOT;
    char* pb = smem + pf * SLOT;
    const bool do_stage = (t + 2 < NT);
    #pragma unroll
    for (int p = 0; p < 2; ++p) {
      bf16x8 af[4], bfr[4];
      #pragma unroll
      for (int m_ = 0; m_ < 4; ++m_)
        af[m_] = *(const bf16x8*)(sb + abase[m_] + ((((p << 2) + lkc) ^ aswz[m_]) << 4));
      #pragma unroll
      for (int n_ = 0; n_ < 4; ++n_)
        bfr[n_] = *(const bf16x8*)(sb + bbase[n_] + ((((p << 2) + lkc) ^ bswz[n_]) << 4));
      if (do_stage) {
        #pragma unroll
        for (int jj = 0; jj < 3; ++jj) {
          const int j = p * 3 + jj;
          gload16((j < JA ? A : Bt) + soff[j] + (t + 2) * BK,
                  (unsigned short*)(pb + (tid + j * 512) * 16));
        }
      }
      __builtin_amdgcn_s_barrier();
      __builtin_amdgcn_s_setprio(1);
      #pragma unroll
      for (int m_ = 0; m_ < 4; ++m_)
        #pragma unroll
        for (int n_ = 0; n_ < 4; ++n_)
          acc[m_][n_] = __builtin_amdgcn_mfma_f32_16x16x32_bf16(
              af[m_], bfr[n_], acc[m_][n_], 0, 0, 0);
      __builtin_amdgcn_s_setprio(0);
      if (p == 1) {
        if (t < NT - 2)       { VMCNT(6); }
        else if (t == NT - 2) { VMCNT(0); }
      }
      __builtin_amdgcn_s_barrier();
      __builtin_amdgcn_sched_barrier(0);
    }
    cur = (cur == 2) ? 0 : cur + 1;
    pf  = (pf == 2) ? 0 : pf + 1;
  }

  const int colq = l & 15;
  const int rowq = (l >> 4) * 4;
  const int e = *eidx_p;
  const float* brow = bias + (size_t)e * N;
  #pragma unroll
  for (int n_ = 0; n_ < 4; ++n_) {
    const int col = n0 + wn * 64 + n_ * 16 + colq;
    const float bv = brow[col];
    #pragma unroll
    for (int f = 0; f < 4; ++f)
      #pragma unroll
      for (int r = 0; r < 4; ++r) {
        const int row = m0 + wm * 64 + f * 16 + rowq + r;
        Cf[(size_t)row * N + col] = acc[f][n_][r] + bv;
      }
  }
}

// ---------------------------------------------------------------------------
extern "C" void kernel_launch(void* const* d_in, const int* in_sizes, int n_in,
                              void* d_out, int out_size, void* d_ws, size_t ws_size,
                              hipStream_t stream)
{
  const float* inputs     = (const float*)d_in[0];
  const float* basis_up   = (const float*)d_in[1];
  const float* basis_down = (const float*)d_in[2];
  const float* cup        = (const float*)d_in[3];
  const float* cdn        = (const float*)d_in[4];
  const float* bias       = (const float*)d_in[5];
  const int*   eidx       = (const int*)d_in[6];
  float*       out        = (float*)d_out;

  char* ws = (char*)d_ws;
  unsigned short* A_bf   = (unsigned short*)(ws);                  // 16 MB
  unsigned short* hidden = (unsigned short*)(ws + (16u << 20));    // 64 MB
  unsigned short* WupT   = (unsigned short*)(ws + (80u << 20));    //  8 MB
  unsigned short* WdnT   = (unsigned short*)(ws + (88u << 20));    //  8 MB

  // reconstruct(+transpose) + cvt
  mem_kernel<<<2560, 256, 0, stream>>>(
      inputs, basis_up, basis_down, cup, cdn, eidx, A_bf, WupT, WdnT);

  // hidden = gelu(A_bf @ WupT^T)   M=8192 N=4096 K=1024; grid 512
  gemm8p<256, 256, 8, 8><<<512, 512, 0, stream>>>(
      A_bf, WupT, hidden, NTOK, HDDIM, DMODEL);

  // out = hidden @ WdnT^T + bias   M=8192 N=1024 K=4096; grid 256, BK=64
  gemm_k64<8, 4><<<256, 512, 0, stream>>>(
      hidden, WdnT, out, bias, eidx, NTOK, DMODEL, HDDIM);
}

// Round 12
// 317.986 us; speedup vs baseline: 3.2469x; 1.1113x over previous
//
#include <hip/hip_runtime.h>
#include <cstdint>

#define NTOK 8192
#define DMODEL 1024
#define HDDIM 4096
#define NVEC 32

typedef float f32x4_v __attribute__((ext_vector_type(4)));
typedef __bf16 bf16x8 __attribute__((ext_vector_type(8)));
typedef unsigned short u16x4 __attribute__((ext_vector_type(4)));
typedef unsigned short u16x8 __attribute__((ext_vector_type(8)));

__device__ __forceinline__ unsigned short f2bf(float f) {
  union { float f; uint32_t u; } x; x.f = f;
  uint32_t r = (x.u + 0x7FFFu + ((x.u >> 16) & 1u)) >> 16;
  return (unsigned short)r;
}

__device__ __forceinline__ float gelu_fast(float x) {
  float t = x * x;
  float z = x * (2.3022082f + 0.1029440f * t);
  float e = exp2f(-z);
  return x / (1.0f + e);
}

#define VMCNT(n) asm volatile("s_waitcnt vmcnt(" #n ")" ::: "memory")

__device__ __forceinline__ void gload16(const unsigned short* g, unsigned short* lds)
{
  __builtin_amdgcn_global_load_lds((__attribute__((address_space(1))) void*)g,
                                   (__attribute__((address_space(3))) void*)lds,
                                   16, 0, 0);
}

// ---------------------------------------------------------------------------
// Reconstruct + transpose body (local-thread-id version): tile 16x256.
// outT[y][x] (bf16, ld=X) = sum_v c[v]*basis[v][x][y]
// ---------------------------------------------------------------------------
__device__ __forceinline__
void reconstruct_body(const float* __restrict__ basis,
                      const float* __restrict__ coeffs,
                      int e, unsigned short* __restrict__ outT,
                      int X, int Y, int tile, int stag, char* smem, int t)
{
  float (*lds)[260] = (float (*)[260])smem;
  const int xtiles = X >> 4;
  const int bx = tile % xtiles;
  const int by = tile / xtiles;
  const int x0 = bx << 4, y0 = by << 8;
  const int w  = t >> 6, l = t & 63;

  f32x4_v acc[4];
  #pragma unroll
  for (int i = 0; i < 4; ++i) acc[i] = (f32x4_v){0.f, 0.f, 0.f, 0.f};

  const size_t mat = (size_t)X * (size_t)Y;
  uint32_t roff[4];
  #pragma unroll
  for (int i = 0; i < 4; ++i)
    roff[i] = (uint32_t)(x0 + w * 4 + i) * (uint32_t)Y + (uint32_t)(y0 + l * 4);

  #pragma unroll 4
  for (int vv = 0; vv < NVEC; ++vv) {
    const int v = (vv + stag) & (NVEC - 1);
    const float cv = coeffs[e * NVEC + v];
    const float* pv = basis + (size_t)v * mat;
    #pragma unroll
    for (int i = 0; i < 4; ++i) {
      f32x4_v d = __builtin_nontemporal_load((const f32x4_v*)(pv + roff[i]));
      acc[i] += cv * d;
    }
  }

  #pragma unroll
  for (int i = 0; i < 4; ++i)
    *(f32x4_v*)&lds[w * 4 + i][l * 4] = acc[i];
  __syncthreads();

  const int y = y0 + t;
  u16x8 o0, o1;
  #pragma unroll
  for (int x = 0; x < 8; ++x)  o0[x] = f2bf(lds[x][t]);
  #pragma unroll
  for (int x = 0; x < 8; ++x)  o1[x] = f2bf(lds[8 + x][t]);
  unsigned short* dst = outT + (size_t)y * X + x0;
  *(u16x8*)dst = o0;
  *(u16x8*)(dst + 8) = o1;
}

// ---------------------------------------------------------------------------
// Phase 1: rec_up (0..1023) | cvt (1024..1535).  256 threads.
// ---------------------------------------------------------------------------
__global__ __launch_bounds__(256)
void p1_kernel(const float* __restrict__ inputs,
               const float* __restrict__ basis_up,
               const float* __restrict__ cup,
               const int* __restrict__ eidx_p,
               unsigned short* __restrict__ A_bf,
               unsigned short* __restrict__ WupT)
{
  __shared__ __align__(16) char smem[16 * 260 * 4];
  const int bid = blockIdx.x;
  if (bid < 1024) {
    reconstruct_body(basis_up, cup, *eidx_p, WupT, DMODEL, HDDIM, bid, bid,
                     smem, threadIdx.x);
  } else {
    const int n4 = NTOK * DMODEL / 4;
    const int stride = 512 * 256;
    for (int i = (bid - 1024) * 256 + threadIdx.x; i < n4; i += stride) {
      f32x4_v v = ((const f32x4_v*)inputs)[i];
      u16x4 u;
      #pragma unroll
      for (int j = 0; j < 4; ++j) u[j] = f2bf(v[j]);
      ((u16x4*)A_bf)[i] = u;
    }
  }
}

// ---------------------------------------------------------------------------
// Phase 2: g1 (even bids: tile bid/2) OVERLAPPED with rec_dn (odd bids:
// two 16x256 tiles per block, 512 threads as two independent halves).
// Uniform 128 KB LDS -> 1 block/CU -> device-level CU partitioning:
// rec CUs saturate HBM while g1 CUs run MFMA out of L2/L3.
// ---------------------------------------------------------------------------
__global__ __launch_bounds__(512)
void p2_kernel(const unsigned short* __restrict__ A,
               const unsigned short* __restrict__ Bt,
               unsigned short* __restrict__ Cbf,
               const float* __restrict__ basis_down,
               const float* __restrict__ cdn,
               const int* __restrict__ eidx_p,
               unsigned short* __restrict__ WdnT)
{
  constexpr int BM = 256, BN = 256, BK = 32, CHM = 8, CHN = 8;
  constexpr int FM = BM / 32, FN = BN / 64;
  constexpr int P = (FM * FN) / 16;
  constexpr int SLOT = (BM + BN) * BK * 2;     // 32 KB
  constexpr int L = SLOT / 16 / 512;           // 4
  constexpr int LPP = L / P;
  constexpr int ACH = BM * 4;
  constexpr int JA = ACH / 512;                // 2

  __shared__ __align__(16) char smem[4 * SLOT];  // 128 KB

  const int bid = blockIdx.x;

  if (bid & 1) {
    // ---- rec_dn: two tiles, halves of the block ----
    const int half = threadIdx.x >> 8;
    const int tile = (bid >> 1) * 2 + half;
    reconstruct_body(basis_down, cdn, *eidx_p, WdnT, HDDIM, DMODEL,
                     tile, bid + half, smem + half * 16640, threadIdx.x & 255);
    return;
  }

  // ---- g1 tile ----
  const int gtile = bid >> 1;
  const int K = DMODEL, N = HDDIM;
  const int ncn = (N / BN) / CHN;
  const int xcd = gtile & 7;
  const int idx = gtile >> 3;
  const int bm  = (xcd / ncn) * CHM + idx / CHN;
  const int bn  = (xcd % ncn) * CHN + idx % CHN;
  const int m0 = bm * BM, n0 = bn * BN;

  const int tid = threadIdx.x;
  const int w = tid >> 6, l = tid & 63;
  const int wm = w >> 2, wn = w & 3;
  const int lrow = l & 15, lkc = l >> 4;

  uint32_t soff[L];
  #pragma unroll
  for (int j = 0; j < L; ++j) {
    const int q = tid + j * 512;
    if (j < JA) {
      const int r = q >> 2, cs = (q & 3) ^ ((r >> 1) & 3);
      soff[j] = (uint32_t)(m0 + r) * (uint32_t)K + cs * 8;
    } else {
      const int q2 = q - ACH;
      const int r = q2 >> 2, cs = (q2 & 3) ^ ((r >> 1) & 3);
      soff[j] = (uint32_t)(n0 + r) * (uint32_t)K + cs * 8;
    }
  }

  int aoff[FM], boff[FN];
  #pragma unroll
  for (int f = 0; f < FM; ++f) {
    const int r = wm * (BM / 2) + f * 16 + lrow;
    aoff[f] = r * 64 + ((lkc ^ ((r >> 1) & 3)) << 4);
  }
  #pragma unroll
  for (int n_ = 0; n_ < FN; ++n_) {
    const int r = wn * (BN / 4) + n_ * 16 + lrow;
    boff[n_] = BM * 64 + r * 64 + ((lkc ^ ((r >> 1) & 3)) << 4);
  }

  f32x4_v acc[FM][FN];
  #pragma unroll
  for (int f = 0; f < FM; ++f)
    #pragma unroll
    for (int n_ = 0; n_ < FN; ++n_) acc[f][n_] = (f32x4_v){0.f, 0.f, 0.f, 0.f};

  const int NT = K / BK;

  for (int tt = 0; tt < 3; ++tt) {
    char* sb = smem + tt * SLOT;
    #pragma unroll
    for (int j = 0; j < L; ++j)
      gload16((j < JA ? A : Bt) + soff[j] + tt * BK,
              (unsigned short*)(sb + (tid + j * 512) * 16));
  }
  VMCNT(8);
  __builtin_amdgcn_s_barrier();
  __builtin_amdgcn_sched_barrier(0);

  bf16x8 bfr[FN];
  for (int t = 0; t < NT; ++t) {
    const char* sb = smem + (t & 3) * SLOT;
    char* pb = smem + ((t + 3) & 3) * SLOT;
    const bool do_stage = (t + 3 < NT);
    #pragma unroll
    for (int p = 0; p < P; ++p) {
      bf16x8 af[4];
      #pragma unroll
      for (int m_ = 0; m_ < 4; ++m_)
        af[m_] = *(const bf16x8*)(sb + aoff[p * 4 + m_]);
      if (p == 0) {
        #pragma unroll
        for (int n_ = 0; n_ < FN; ++n_)
          bfr[n_] = *(const bf16x8*)(sb + boff[n_]);
      }
      if (do_stage) {
        #pragma unroll
        for (int jj = 0; jj < LPP; ++jj) {
          const int j = p * LPP + jj;
          gload16((j < JA ? A : Bt) + soff[j] + (t + 3) * BK,
                  (unsigned short*)(pb + (tid + j * 512) * 16));
        }
      }
      __builtin_amdgcn_s_barrier();
      __builtin_amdgcn_s_setprio(1);
      #pragma unroll
      for (int m_ = 0; m_ < 4; ++m_)
        #pragma unroll
        for (int n_ = 0; n_ < FN; ++n_)
          acc[p * 4 + m_][n_] = __builtin_amdgcn_mfma_f32_16x16x32_bf16(
              af[m_], bfr[n_], acc[p * 4 + m_][n_], 0, 0, 0);
      __builtin_amdgcn_s_setprio(0);
      if (p == P - 1) {
        if (t < NT - 3)       { VMCNT(8); }
        else if (t == NT - 3) { VMCNT(4); }
        else if (t == NT - 2) { VMCNT(0); }
      }
      __builtin_amdgcn_s_barrier();
      __builtin_amdgcn_sched_barrier(0);
    }
  }

  const int colq = l & 15;
  const int rowq = (l >> 4) * 4;
  #pragma unroll
  for (int f = 0; f < FM; ++f)
    #pragma unroll
    for (int n_ = 0; n_ < FN; ++n_) {
      const int col = n0 + wn * (BN / 4) + n_ * 16 + colq;
      #pragma unroll
      for (int r = 0; r < 4; ++r) {
        const int row = m0 + wm * (BM / 2) + f * 16 + rowq + r;
        Cbf[(size_t)row * N + col] = f2bf(gelu_fast(acc[f][n_][r]));
      }
    }
}

// ---------------------------------------------------------------------------
// g2: BM=128 BN=256 BK=64, 3-slot ring (144KB), lead-2, P=2 (R11, ~87us)
// ---------------------------------------------------------------------------
template<int CHM, int CHN>
__global__ __launch_bounds__(512)
void gemm_k64(const unsigned short* __restrict__ A,
              const unsigned short* __restrict__ Bt,
              float* __restrict__ Cf,
              const float* __restrict__ bias,
              const int* __restrict__ eidx_p,
              int M, int N, int K)
{
  constexpr int BM = 128, BN = 256, BK = 64;
  constexpr int SLOT = (BM + BN) * BK * 2;
  constexpr int L = 6, JA = 2;
  __shared__ __align__(16) char smem[3 * SLOT];

  const int nb  = N / BN;
  const int ncn = nb / CHN;
  const int xcd = blockIdx.x & 7;
  const int idx = blockIdx.x >> 3;
  const int bm  = (xcd / ncn) * CHM + idx / CHN;
  const int bn  = (xcd % ncn) * CHN + idx % CHN;
  const int m0 = bm * BM, n0 = bn * BN;

  const int tid = threadIdx.x;
  const int w = tid >> 6, l = tid & 63;
  const int wm = w >> 2, wn = w & 3;
  const int lrow = l & 15, lkc = l >> 4;

  uint32_t soff[L];
  #pragma unroll
  for (int j = 0; j < L; ++j) {
    const int q = tid + j * 512;
    if (j < JA) {
      const int r = q >> 3, cs = (q & 7) ^ (r & 7);
      soff[j] = (uint32_t)(m0 + r) * (uint32_t)K + cs * 8;
    } else {
      const int q2 = q - 1024;
      const int r = q2 >> 3, cs = (q2 & 7) ^ (r & 7);
      soff[j] = (uint32_t)(n0 + r) * (uint32_t)K + cs * 8;
    }
  }

  int abase[4], aswz[4], bbase[4], bswz[4];
  #pragma unroll
  for (int f = 0; f < 4; ++f) {
    const int r = wm * 64 + f * 16 + lrow;
    abase[f] = r * 128; aswz[f] = r & 7;
  }
  #pragma unroll
  for (int n_ = 0; n_ < 4; ++n_) {
    const int r = wn * 64 + n_ * 16 + lrow;
    bbase[n_] = 16384 + r * 128; bswz[n_] = r & 7;
  }

  f32x4_v acc[4][4];
  #pragma unroll
  for (int f = 0; f < 4; ++f)
    #pragma unroll
    for (int n_ = 0; n_ < 4; ++n_) acc[f][n_] = (f32x4_v){0.f, 0.f, 0.f, 0.f};

  const int NT = K / BK;

  for (int tt = 0; tt < 2; ++tt) {
    char* sb = smem + tt * SLOT;
    #pragma unroll
    for (int j = 0; j < L; ++j)
      gload16((j < JA ? A : Bt) + soff[j] + tt * BK,
              (unsigned short*)(sb + (tid + j * 512) * 16));
  }
  VMCNT(6);
  __builtin_amdgcn_s_barrier();
  __builtin_amdgcn_sched_barrier(0);

  int cur = 0, pf = 2;
  for (int t = 0; t < NT; ++t) {
    const char* sb = smem + cur * SLOT;
    char* pb = smem + pf * SLOT;
    const bool do_stage = (t + 2 < NT);
    #pragma unroll
    for (int p = 0; p < 2; ++p) {
      bf16x8 af[4], bfr[4];
      #pragma unroll
      for (int m_ = 0; m_ < 4; ++m_)
        af[m_] = *(const bf16x8*)(sb + abase[m_] + ((((p << 2) + lkc) ^ aswz[m_]) << 4));
      #pragma unroll
      for (int n_ = 0; n_ < 4; ++n_)
        bfr[n_] = *(const bf16x8*)(sb + bbase[n_] + ((((p << 2) + lkc) ^ bswz[n_]) << 4));
      if (do_stage) {
        #pragma unroll
        for (int jj = 0; jj < 3; ++jj) {
          const int j = p * 3 + jj;
          gload16((j < JA ? A : Bt) + soff[j] + (t + 2) * BK,
                  (unsigned short*)(pb + (tid + j * 512) * 16));
        }
      }
      __builtin_amdgcn_s_barrier();
      __builtin_amdgcn_s_setprio(1);
      #pragma unroll
      for (int m_ = 0; m_ < 4; ++m_)
        #pragma unroll
        for (int n_ = 0; n_ < 4; ++n_)
          acc[m_][n_] = __builtin_amdgcn_mfma_f32_16x16x32_bf16(
              af[m_], bfr[n_], acc[m_][n_], 0, 0, 0);
      __builtin_amdgcn_s_setprio(0);
      if (p == 1) {
        if (t < NT - 2)       { VMCNT(6); }
        else if (t == NT - 2) { VMCNT(0); }
      }
      __builtin_amdgcn_s_barrier();
      __builtin_amdgcn_sched_barrier(0);
    }
    cur = (cur == 2) ? 0 : cur + 1;
    pf  = (pf == 2) ? 0 : pf + 1;
  }

  const int colq = l & 15;
  const int rowq = (l >> 4) * 4;
  const int e = *eidx_p;
  const float* brow = bias + (size_t)e * N;
  #pragma unroll
  for (int n_ = 0; n_ < 4; ++n_) {
    const int col = n0 + wn * 64 + n_ * 16 + colq;
    const float bv = brow[col];
    #pragma unroll
    for (int f = 0; f < 4; ++f)
      #pragma unroll
      for (int r = 0; r < 4; ++r) {
        const int row = m0 + wm * 64 + f * 16 + rowq + r;
        Cf[(size_t)row * N + col] = acc[f][n_][r] + bv;
      }
  }
}

// ---------------------------------------------------------------------------
extern "C" void kernel_launch(void* const* d_in, const int* in_sizes, int n_in,
                              void* d_out, int out_size, void* d_ws, size_t ws_size,
                              hipStream_t stream)
{
  const float* inputs     = (const float*)d_in[0];
  const float* basis_up   = (const float*)d_in[1];
  const float* basis_down = (const float*)d_in[2];
  const float* cup        = (const float*)d_in[3];
  const float* cdn        = (const float*)d_in[4];
  const float* bias       = (const float*)d_in[5];
  const int*   eidx       = (const int*)d_in[6];
  float*       out        = (float*)d_out;

  char* ws = (char*)d_ws;
  unsigned short* A_bf   = (unsigned short*)(ws);                  // 16 MB
  unsigned short* hidden = (unsigned short*)(ws + (16u << 20));    // 64 MB
  unsigned short* WupT   = (unsigned short*)(ws + (80u << 20));    //  8 MB
  unsigned short* WdnT   = (unsigned short*)(ws + (88u << 20));    //  8 MB

  // P1: rec_up + cvt (HBM-bound)
  p1_kernel<<<1536, 256, 0, stream>>>(
      inputs, basis_up, cup, eidx, A_bf, WupT);

  // P2: g1 (even blocks) overlapped with rec_dn (odd blocks)
  p2_kernel<<<1024, 512, 0, stream>>>(
      A_bf, WupT, hidden, basis_down, cdn, eidx, WdnT);

  // P3: out = hidden @ WdnT^T + bias
  gemm_k64<8, 4><<<256, 512, 0, stream>>>(
      hidden, WdnT, out, bias, eidx, NTOK, DMODEL, HDDIM);
}